// Round 19
// baseline (115.151 us; speedup 1.0000x reference)
//
#include <hip/hip_runtime.h>
#include <hip/hip_bf16.h>

#define BATCH 4
#define NSEQ  4096
#define CDIM  256
#define CQK   32
#define L2E   1.44269504088896340736f

typedef short bf16x8 __attribute__((ext_vector_type(8)));   // 8 bf16 in 4 VGPRs
typedef float f32x16 __attribute__((ext_vector_type(16)));
typedef unsigned short u16;
typedef unsigned int   u32;
typedef unsigned int   u32x4 __attribute__((ext_vector_type(4)));

__device__ __forceinline__ u32 pk2(float lo, float hi) {    // v_cvt_pk_bf16_f32
  u16 a = __builtin_bit_cast(u16, __float2bfloat16(lo));
  u16 b = __builtin_bit_cast(u16, __float2bfloat16(hi));
  return (u32)a | ((u32)b << 16);
}
__device__ __forceinline__ bf16x8 ld8(const u16* p) {
  uint4 u = *(const uint4*)p;
  return __builtin_bit_cast(bf16x8, u);
}
// raw v_exp_f32 via builtin (hazard-safe; inline-asm version failed r9 at absmax 2.69)
__device__ __forceinline__ float exp2_raw(float x) {
#if __has_builtin(__builtin_amdgcn_exp2f)
  return __builtin_amdgcn_exp2f(x);
#else
  return exp2f(x);
#endif
}

// ---------------- weight prep: W[k][c] (f32) -> WT[c][k] (bf16); WfT pre-scaled by L2E --
__global__ __launch_bounds__(64) void prep_kernel(
    const float* __restrict__ Wf, const float* __restrict__ Wg, const float* __restrict__ Wh,
    u16* __restrict__ wfT, u16* __restrict__ wgT, u16* __restrict__ whT) {
  const int cb = blockIdx.x, t = threadIdx.x;
#pragma unroll
  for (int j = 0; j < 4; ++j) {
    const int k = t + j * 64;
    if (cb < 32) {
      wfT[cb * 256 + k] = (u16)(pk2(Wf[k * CQK + cb] * L2E, 0.f) & 0xFFFF);
    } else if (cb < 64) {
      const int c = cb - 32;
      wgT[c * 256 + k] = (u16)(pk2(Wg[k * CQK + c], 0.f) & 0xFFFF);
    } else {
      const int c = cb - 64;
      whT[c * 256 + k] = (u16)(pk2(Wh[k * CDIM + c], 0.f) & 0xFFFF);
    }
  }
}

// ---------------- MFMA projection -> FRAGMENT-PACKED outputs (unchanged from r17) -------
// fP[b*128+kc][ks(2)][lane(64)][8]  : A-frag tiles for QK   (kc = 32-key chunk)
// hP[(b*8+cg)*128+kc][ks(2)][lane(64)][8] : B-frag tiles for PV (cg = 32-ch group)
__global__ __launch_bounds__(256, 1) void proj_kernel(
    const float* __restrict__ x,
    const float* __restrict__ bfv, const float* __restrict__ bgv, const float* __restrict__ bhv,
    const u16* __restrict__ wfT, const u16* __restrict__ wgT, const u16* __restrict__ whT,
    u16* __restrict__ fP, u16* __restrict__ g_ws, u16* __restrict__ hP) {
  const int tid   = threadIdx.x;
  const int lan   = tid & 63;
  const int lan31 = lan & 31;
  const int g2    = lan >> 5;
  const int w     = tid >> 6;
  const int half  = w >> 1;                     // channel half 0/1
  const int row0  = blockIdx.x * 64 + (w & 1) * 32;
  const int b     = row0 >> 12;
  const int kcg   = row0 >> 5;                  // global kc = b*128 + (row0&4095)>>5

  bf16x8 xf[16];
  const float* xr = x + ((size_t)row0 + lan31) * CDIM + g2 * 8;
#pragma unroll
  for (int ks = 0; ks < 16; ++ks) {
    float4 a = *(const float4*)(xr + ks * 16);
    float4 c = *(const float4*)(xr + ks * 16 + 4);
    u32x4 u = { pk2(a.x, a.y), pk2(a.z, a.w), pk2(c.x, c.y), pk2(c.z, c.w) };
    xf[ks] = __builtin_bit_cast(bf16x8, u);
  }

  { // f (half 0, packed) or g (half 1, row-major): D[m=row(key)][n=c]
    const u16*  wT   = half ? wgT : wfT;
    const float bias = half ? bgv[lan31] : bfv[lan31] * L2E;
    f32x16 acc;
#pragma unroll
    for (int r = 0; r < 16; ++r) acc[r] = bias;
    const u16* wp = wT + lan31 * 256 + g2 * 8;
#pragma unroll
    for (int ks = 0; ks < 16; ++ks)
      acc = __builtin_amdgcn_mfma_f32_32x32x16_bf16(xf[ks], ld8(wp + ks * 16), acc, 0, 0, 0);
    if (half) {
#pragma unroll
      for (int r = 0; r < 16; ++r) {
        const int row = (r & 3) + 8 * (r >> 2) + 4 * g2;
        g_ws[((size_t)row0 + row) * CQK + lan31] = (u16)(pk2(acc[r], 0.f) & 0xFFFF);
      }
    } else {
      u16* fb = fP + (size_t)kcg * 1024
              + (lan31 >> 4) * 512 + ((lan31 >> 3) & 1) * 256 + (lan31 & 7);
#pragma unroll
      for (int r = 0; r < 16; ++r) {
        const int crow = (r & 3) + 8 * (r >> 2) + 4 * g2;   // key row within chunk
        fb[crow * 8] = (u16)(pk2(acc[r], 0.f) & 0xFFFF);
      }
    }
  }

#pragma unroll
  for (int t = 0; t < 4; ++t) {
    const int ct = half * 128 + t * 32;
    f32x16 acc;
#pragma unroll
    for (int r = 0; r < 16; ++r)
      acc[r] = bhv[ct + (r & 3) + 8 * (r >> 2) + 4 * g2];
    const u16* wp = whT + (size_t)(ct + lan31) * 256 + g2 * 8;
#pragma unroll
    for (int ks = 0; ks < 16; ++ks)
      acc = __builtin_amdgcn_mfma_f32_32x32x16_bf16(ld8(wp + ks * 16), xf[ks], acc, 0, 0, 0);
    const int cg = half * 4 + t;
    u16* hb = hP + ((size_t)(b * 8 + cg) * 128 + ((row0 & (NSEQ - 1)) >> 5)) * 1024
            + (lan31 >> 4) * 512 + ((lan31 >> 3) & 1) * 256 + (lan31 & 7);
#pragma unroll
    for (int r = 0; r < 16; ++r) {
      const int crow = (r & 3) + 8 * (r >> 2) + 4 * g2;     // channel row within group
      hb[crow * 8] = (u16)(pk2(acc[r], 0.f) & 0xFFFF);
    }
  }
}

// ---------------- flash attention: owner-rotation softmax, no key split ------------------
// Grid 512 = 4b x 64 q-tiles(64q) x 2 cb. Block = 8 waves = 2 qh x 4 cg; wave owns a
// 32q x 32ch output tile over ALL 4096 keys (no combine). Per 32-key chunk c, wave with
// cg==c&3 computes QK+softmax+pack for its qh (once per block), exchanged via a
// TRIPLE-buffered LDS slot (double provably races under 1 barrier/iter). l = P.ones via
// MFMA on the cg==3 wave -> no sum tree, l lands in o's row layout.
// mfma_f32_32x32x16_bf16: A[row=l&31][k=(l>>5)*8+i], B[k=(l>>5)*8+i][col=l&31],
//   D[row=(r&3)+8*(r>>2)+4*(l>>5)][col=l&31]
__global__ __launch_bounds__(512, 4) void attn_kernel(
    const float* __restrict__ x, const float* __restrict__ gamma_p,
    const u16* __restrict__ fP, const u16* __restrict__ g_ws,
    const u16* __restrict__ hP, float* __restrict__ out) {
  __shared__ u32x4 xb[3][2][2][64];             // [slot][qh][fr][lane] 12KB P-exchange
  __shared__ float lsh[2][32];                  // per-qh row sums

  const int tid   = threadIdx.x;
  const int lan   = tid & 63;
  const int lan31 = lan & 31;
  const int g2    = lan >> 5;
  const int w     = tid >> 6;
  const int qh    = w >> 2;                     // query half (32 rows)
  const int cgl   = w & 3;                      // channel group within cb
  const int bid   = blockIdx.x;
  const int xcd   = bid & 7;
  const int b     = xcd >> 1;
  const int inner = bid >> 3;                   // 0..63
  const int cb    = inner & 1;
  const int n0    = ((((xcd & 1) << 5) | (inner >> 1))) * 64;

  const float gamma = gamma_p[0];

  // g fragments for this wave's qh (QK B-operand)
  const u16* gp = g_ws + ((size_t)b * NSEQ + n0 + qh * 32 + lan31) * CQK + g2 * 8;
  bf16x8 bg0 = ld8(gp), bg1 = ld8(gp + 16);

  const u32x4 onesu = {0x3F803F80u, 0x3F803F80u, 0x3F803F80u, 0x3F803F80u};
  const bf16x8 ones = __builtin_bit_cast(bf16x8, onesu);

  f32x16 o, lacc, zfrag;
#pragma unroll
  for (int r = 0; r < 16; ++r) zfrag[r] = 0.f;
  o = zfrag; lacc = zfrag;

  const u16* fbase = fP + (size_t)b * 128 * 1024 + lan * 8;   // chunk stride 1024 elems
  const u16* hpk   = hP + (size_t)(b * 8 + cb * 4 + cgl) * 128 * 1024 + lan * 8;

  // f fragments for my next owned chunk (first owned chunk == cgl)
  bf16x8 mf0 = ld8(fbase + (size_t)cgl * 1024);
  bf16x8 mf1 = ld8(fbase + (size_t)cgl * 1024 + 512);

  auto sm_pack = [&](int slot) {
    f32x16 s = __builtin_amdgcn_mfma_f32_32x32x16_bf16(mf0, bg0, zfrag, 0, 0, 0);
    s        = __builtin_amdgcn_mfma_f32_32x32x16_bf16(mf1, bg1, s,     0, 0, 0);
    float pv[16];
#pragma unroll
    for (int r = 0; r < 16; ++r) pv[r] = exp2_raw(s[r]);
    u32 q0a = pk2(pv[0],pv[1]),   q0b = pk2(pv[2],pv[3]);
    u32 q1a = pk2(pv[4],pv[5]),   q1b = pk2(pv[6],pv[7]);
    u32 q2a = pk2(pv[8],pv[9]),   q2b = pk2(pv[10],pv[11]);
    u32 q3a = pk2(pv[12],pv[13]), q3b = pk2(pv[14],pv[15]);
    auto r02a = __builtin_amdgcn_permlane32_swap(q0a, q1a, false, false);
    auto r13a = __builtin_amdgcn_permlane32_swap(q0b, q1b, false, false);
    auto r02b = __builtin_amdgcn_permlane32_swap(q2a, q3a, false, false);
    auto r13b = __builtin_amdgcn_permlane32_swap(q2b, q3b, false, false);
    u32x4 u0 = {(u32)r02a[0], (u32)r13a[0], (u32)r02a[1], (u32)r13a[1]};
    u32x4 u1 = {(u32)r02b[0], (u32)r13b[0], (u32)r02b[1], (u32)r13b[1]};
    xb[slot][qh][0][lan] = u0;
    xb[slot][qh][1][lan] = u1;
  };

  // prologue: cg0 packs chunk 0 into slot 0, then advances its f to chunk 4
  if (cgl == 0) {
    sm_pack(0);
    mf0 = ld8(fbase + 4 * 1024);
    mf1 = ld8(fbase + 4 * 1024 + 512);
  }
  __syncthreads();

  bf16x8 ha = ld8(hpk), hb = ld8(hpk + 512);    // h chunk 0
  hpk += 1024;

  for (int c = 0; c < 128; ++c) {
    // owner of chunk c+1 packs it (f already resident), then preloads f for c+5
    if (cgl == ((c + 1) & 3) && c + 1 < 128) {
      sm_pack((c + 1) % 3);
      mf0 = ld8(fbase + (size_t)(c + 5) * 1024);
      mf1 = ld8(fbase + (size_t)(c + 5) * 1024 + 512);
    }
    __syncthreads();
    bf16x8 ap0 = __builtin_bit_cast(bf16x8, xb[c % 3][qh][0][lan]);
    bf16x8 ap1 = __builtin_bit_cast(bf16x8, xb[c % 3][qh][1][lan]);
    o = __builtin_amdgcn_mfma_f32_32x32x16_bf16(ap0, ha, o, 0, 0, 0);
    o = __builtin_amdgcn_mfma_f32_32x32x16_bf16(ap1, hb, o, 0, 0, 0);
    if (cgl == 3) {                             // l += P . ones (row sums)
      lacc = __builtin_amdgcn_mfma_f32_32x32x16_bf16(ap0, ones, lacc, 0, 0, 0);
      lacc = __builtin_amdgcn_mfma_f32_32x32x16_bf16(ap1, ones, lacc, 0, 0, 0);
    }
    ha = ld8(hpk); hb = ld8(hpk + 512);         // roll h to chunk c+1 (overrun in-bounds)
    hpk += 1024;
  }

  // broadcast l (all cols of lacc equal; 2 lanes per wave cover all 32 rows)
  if (cgl == 3 && lan31 == 0) {
#pragma unroll
    for (int r = 0; r < 16; ++r) {
      const int row = (r & 3) + 8 * (r >> 2) + 4 * g2;
      lsh[qh][row] = lacc[r];
    }
  }
  __syncthreads();

  // epilogue: y = gamma * O / l + x
  const size_t orow = (size_t)b * NSEQ + n0 + qh * 32;
#pragma unroll
  for (int r = 0; r < 16; ++r) {
    const int row = (r & 3) + 8 * (r >> 2) + 4 * g2;
    const float gi = gamma / lsh[qh][row];
    const size_t i0 = (orow + row) * CDIM + cb * 128 + cgl * 32 + lan31;
    out[i0] = fmaf(gi, o[r], x[i0]);
  }
}

extern "C" void kernel_launch(void* const* d_in, const int* in_sizes, int n_in,
                              void* d_out, int out_size, void* d_ws, size_t ws_size,
                              hipStream_t stream) {
  const float* x     = (const float*)d_in[0];
  const float* Wf    = (const float*)d_in[1];
  const float* bf    = (const float*)d_in[2];
  const float* Wg    = (const float*)d_in[3];
  const float* bg    = (const float*)d_in[4];
  const float* Wh    = (const float*)d_in[5];
  const float* bh    = (const float*)d_in[6];
  const float* gamma = (const float*)d_in[7];
  float* out = (float*)d_out;

  // layout: hP | fP | g | wfT | wgT | whT  (fP before g so f/h overruns land in-bounds)
  u16* hP   = (u16*)d_ws;                                    // 8 MB
  u16* fPp  = hP  + (size_t)BATCH * CDIM * NSEQ;             // 1 MB
  u16* g_ws = fPp + (size_t)BATCH * NSEQ * CQK;              // 1 MB
  u16* wfT  = g_ws + (size_t)BATCH * NSEQ * CQK;             // 16 KB
  u16* wgT  = wfT + (size_t)CQK * CDIM;                      // 16 KB
  u16* whT  = wgT + (size_t)CQK * CDIM;                      // 128 KB

  hipLaunchKernelGGL(prep_kernel, dim3(320), dim3(64), 0, stream,
                     Wf, Wg, Wh, wfT, wgT, whT);
  hipLaunchKernelGGL(proj_kernel, dim3(256), dim3(256), 0, stream,
                     x, bf, bg, bh, wfT, wgT, whT, fPp, g_ws, hP);
  hipLaunchKernelGGL(attn_kernel, dim3(512), dim3(512), 0, stream,
                     x, gamma, fPp, g_ws, hP, out);
}